// Round 3
// baseline (445.906 us; speedup 1.0000x reference)
//
#include <hip/hip_runtime.h>
#include <hip/hip_bf16.h>
#include <hip/hip_cooperative_groups.h>
#include <stdint.h>

namespace cg = cooperative_groups;

// Problem constants
#define M_DIM 8192      // 2*4096 flattened batch
#define K_DIM 2048      // ACTIVE (in)
#define N_DIM 2048      // ACTIVE (out)
#define IN_DIM 4096     // ORIG_IN
#define OUT_DIM 4096    // ORIG_OUT
#define SCALING 2.0f    // 32/16

typedef __attribute__((ext_vector_type(8))) short bf16x8_t;  // 8 bf16 = 4 VGPRs
typedef __attribute__((ext_vector_type(4))) float f32x4_t;

__device__ __forceinline__ void load_lds16(const void* gptr, void* lptr) {
    __builtin_amdgcn_global_load_lds(
        (const __attribute__((address_space(1))) uint32_t*)(uintptr_t)gptr,
        (__attribute__((address_space(3))) uint32_t*)(uintptr_t)lptr,
        16, 0, 0);
}

// LDS fragment read with chunk-XOR de-swizzle (matches stage_call's source
// swizzle): p = qd ^ ((row>>1)&3), 64 B row pitch.
__device__ __forceinline__ bf16x8_t frag_ld(const __hip_bfloat16* buf, int row, int qd) {
    const int p = qd ^ ((row >> 1) & 3);
    return *(const bf16x8_t*)(buf + row * 32 + p * 8);
}

// Stage one 8 KB region: 128 rows x 32 bf16 cols, 512 threads x 16B.
// LDS dest linear (wave-uniform base); chunk swizzle applied to the GLOBAL
// source address (both-sides-or-neither rule).
__device__ __forceinline__ void stage_call(const __hip_bfloat16* __restrict__ G,
                                           int grow0,               // global row of region start
                                           __hip_bfloat16* region,  // LDS tile base (row 0)
                                           int lrow0,               // region start row in tile (0/128)
                                           int w, int l, int k0) {
    const int rr   = w * 16 + (l >> 2);        // row within region 0..127
    const int lrow = lrow0 + rr;               // row within 256-row tile (swizzle key)
    const int kc   = (l & 3) ^ ((lrow >> 1) & 3);
    load_lds16(G + (size_t)(grow0 + rr) * K_DIM + k0 + kc * 8,
               (void*)(region + (size_t)(lrow0 + w * 16) * 32));  // wave-uniform
}

// ---------------------------------------------------------------------------
// MEGA KERNEL (cooperative): all 5 stages in one dispatch.
//   grid = dim3(8,32) = 256 blocks x 512 threads, 128 KiB LDS -> 1 block/CU,
//   256 blocks on 256 CUs: co-residency structurally guaranteed.
// Phase A: fold-W, inv map, gather+cast (independent; block-partitioned).
// grid.sync()  (device-scope fence: cross-XCD visibility of xs/We)
// Phase B: 256x256 quad-buffered counted-vmcnt GEMM (round-2 body, bit-
//          identical accumulation order) -> compact bf16 C.
// grid.sync()
// Phase C: expand compact C -> f32 out with zeros (row-partitioned).
// ---------------------------------------------------------------------------
__global__ void __launch_bounds__(512, 1)
mega_kernel(const float* __restrict__ x,        // [8192][4096]
            const float* __restrict__ Wb,       // [2048][2048]
            const float* __restrict__ bias,     // [2048]
            const float* __restrict__ lA,       // [16][2048]
            const float* __restrict__ lB,       // [2048][16]
            const int* __restrict__ idx,        // [2048] in_indices (sorted)
            const int* __restrict__ oidx,       // [2048] out_indices (sorted)
            __hip_bfloat16* __restrict__ xs,    // ws: [8192][2048]
            __hip_bfloat16* __restrict__ We,    // ws: [2048][2048]
            __hip_bfloat16* __restrict__ Cc,    // ws: [8192][2048]
            int* __restrict__ inv,              // ws: [4096]
            float* __restrict__ out)            // [8192][4096]
{
    __shared__ char smem[131072];               // 128 KiB, reused per phase

    const int tid  = threadIdx.x;
    const int flat = blockIdx.y * 8 + blockIdx.x;   // 0..255

    // ================= Phase A =================
    // A1: fold LoRA into W, cast bf16.  4M elems, 16384/block, 32/thread.
    {
        const size_t e0 = (size_t)flat * 16384;
        #pragma unroll 4
        for (int i = 0; i < 32; ++i) {
            const size_t e = e0 + (size_t)i * 512 + tid;
            const int o = (int)(e >> 11);
            const int k = (int)(e & 2047);
            float acc = Wb[e];
            #pragma unroll
            for (int r = 0; r < 16; ++r)
                acc += SCALING * lB[o * 16 + r] * lA[r * K_DIM + k];
            We[e] = __float2bfloat16(acc);
        }
    }
    // A2: inverse index map (binary search), 16 cols/block.
    if (tid < 16) {
        const int c = flat * 16 + tid;
        int lo = 0, hi = N_DIM;
        while (lo < hi) {
            const int mid = (lo + hi) >> 1;
            if (oidx[mid] < c) lo = mid + 1; else hi = mid;
        }
        inv[c] = (lo < N_DIM && oidx[lo] == c) ? lo : -1;
    }
    // A3: gather active cols + cast bf16.  32 rows/block, 2 rows per LDS pass.
    {
        float* rowbuf = (float*)smem;            // 2 x 4096 f32 = 32 KB
        const int sub  = tid & 255;
        const int half = tid >> 8;               // which of the 2 rows
        const int c0   = sub * 8;
        const int4 i0 = *(const int4*)(idx + c0);
        const int4 i1 = *(const int4*)(idx + c0 + 4);
        for (int pass = 0; pass < 16; ++pass) {
            const int r0 = flat * 32 + pass * 2;
            #pragma unroll
            for (int i = 0; i < 4; ++i) {
                const int f = i * 512 + tid;     // 0..2047 float4 slots
                ((float4*)rowbuf)[f] =
                    ((const float4*)(x + (size_t)r0 * IN_DIM))[f];
            }
            __syncthreads();
            const float* rb = rowbuf + half * IN_DIM;
            union { bf16x8_t v; __hip_bfloat16 h[8]; } u;
            u.h[0] = __float2bfloat16(rb[i0.x]);
            u.h[1] = __float2bfloat16(rb[i0.y]);
            u.h[2] = __float2bfloat16(rb[i0.z]);
            u.h[3] = __float2bfloat16(rb[i0.w]);
            u.h[4] = __float2bfloat16(rb[i1.x]);
            u.h[5] = __float2bfloat16(rb[i1.y]);
            u.h[6] = __float2bfloat16(rb[i1.z]);
            u.h[7] = __float2bfloat16(rb[i1.w]);
            *(bf16x8_t*)(xs + (size_t)(r0 + half) * K_DIM + c0) = u.v;
            __syncthreads();
        }
    }

    cg::this_grid().sync();

    // ================= Phase B: GEMM (round-2 body, unchanged math) ========
    {
        typedef __hip_bfloat16 ldsT;
        ldsT (*lds)[2][256 * 32] = (ldsT(*)[2][256 * 32])smem;  // [4][2][8192]

        const int w   = tid >> 6;        // wave 0..7
        const int l   = tid & 63;
        const int r15 = l & 15;
        const int qd  = l >> 4;
        const int wm  = w >> 2;          // 0..1  (M half: 128 rows)
        const int wn  = w & 3;           // 0..3  (N quarter: 64 cols)
        const int m0  = blockIdx.y * 256;
        const int n0  = blockIdx.x * 256;

        f32x4_t acc[8][4] = {};

        // Prologue: stage K-tiles 0,1,2 (12 vmem instrs/wave).
        #pragma unroll
        for (int t = 0; t < 3; ++t) {
            const int k0 = t * 32;
            stage_call(xs, m0,       lds[t][0], 0,   w, l, k0);
            stage_call(xs, m0 + 128, lds[t][0], 128, w, l, k0);
            stage_call(We, n0,       lds[t][1], 0,   w, l, k0);
            stage_call(We, n0 + 128, lds[t][1], 128, w, l, k0);
        }
        asm volatile("s_waitcnt vmcnt(8)" ::: "memory");  // tile 0 landed
        __builtin_amdgcn_sched_barrier(0);
        __builtin_amdgcn_s_barrier();

        #pragma unroll 4
        for (int tt = 0; tt < 64; ++tt) {
            const int bs  = tt & 3;               // compute buffer
            const int bt  = (tt + 3) & 3;         // stage target (dead buffer)
            const int k0s = ((tt + 3) & 63) * 32;
            const __hip_bfloat16* Ab = lds[bs][0];
            const __hip_bfloat16* Bb = lds[bs][1];

            bf16x8_t af[8], bfr[4];
            #pragma unroll
            for (int i = 0; i < 8; ++i)
                af[i] = frag_ld(Ab, wm * 128 + i * 16 + r15, qd);
            #pragma unroll
            for (int j = 0; j < 4; ++j)
                bfr[j] = frag_ld(Bb, wn * 64 + j * 16 + r15, qd);

            stage_call(xs, m0,       lds[bt][0], 0,   w, l, k0s);
            stage_call(xs, m0 + 128, lds[bt][0], 128, w, l, k0s);
            stage_call(We, n0,       lds[bt][1], 0,   w, l, k0s);
            stage_call(We, n0 + 128, lds[bt][1], 128, w, l, k0s);

            __builtin_amdgcn_s_setprio(1);
            #pragma unroll
            for (int i = 0; i < 8; ++i)
                #pragma unroll
                for (int j = 0; j < 4; ++j)
                    acc[i][j] = __builtin_amdgcn_mfma_f32_16x16x32_bf16(
                        af[i], bfr[j], acc[i][j], 0, 0, 0);
            __builtin_amdgcn_s_setprio(0);

            asm volatile("s_waitcnt vmcnt(8)" ::: "memory");
            __builtin_amdgcn_sched_barrier(0);
            __builtin_amdgcn_s_barrier();
        }
        asm volatile("s_waitcnt vmcnt(0)" ::: "memory");

        // Epilogue: C/D layout col = lane&15, row = qd*4 + reg (m89/m91).
        #pragma unroll
        for (int j = 0; j < 4; ++j) {
            const int gn = n0 + wn * 64 + j * 16 + r15;
            const float bv = bias[gn];
            #pragma unroll
            for (int i = 0; i < 8; ++i) {
                const int gm = m0 + wm * 128 + i * 16 + qd * 4;
                #pragma unroll
                for (int r = 0; r < 4; ++r)
                    Cc[(size_t)(gm + r) * N_DIM + gn] =
                        __float2bfloat16(acc[i][j][r] + bv);
            }
        }
    }

    cg::this_grid().sync();

    // ================= Phase C: expand to full output =================
    {
        for (int rr = 0; rr < 32; ++rr) {
            const int row = flat * 32 + rr;
            const __hip_bfloat16* crow = Cc + (size_t)row * N_DIM;
            #pragma unroll
            for (int p = 0; p < 2; ++p) {
                const int g = (p * 512 + tid) * 4;   // out col
                const int4 iv = *(const int4*)(inv + g);
                float4 v;
                v.x = (iv.x >= 0) ? __bfloat162float(crow[iv.x]) : 0.0f;
                v.y = (iv.y >= 0) ? __bfloat162float(crow[iv.y]) : 0.0f;
                v.z = (iv.z >= 0) ? __bfloat162float(crow[iv.z]) : 0.0f;
                v.w = (iv.w >= 0) ? __bfloat162float(crow[iv.w]) : 0.0f;
                *(float4*)(out + (size_t)row * OUT_DIM + g) = v;
            }
        }
    }
}

// ---------------------------------------------------------------------------
// Fallback path kernels (ws too small): round-2 behavior, unchanged.
// ---------------------------------------------------------------------------
__global__ void fold_w_kernel(const float* __restrict__ Wb,
                              const float* __restrict__ lA,
                              const float* __restrict__ lB,
                              __hip_bfloat16* __restrict__ We) {
    const int k = blockIdx.x * 256 + threadIdx.x;
    const int o = blockIdx.y;
    float acc = Wb[(size_t)o * K_DIM + k];
    #pragma unroll
    for (int r = 0; r < 16; ++r)
        acc += SCALING * lB[o * 16 + r] * lA[r * K_DIM + k];
    We[(size_t)o * K_DIM + k] = __float2bfloat16(acc);
}

__global__ void __launch_bounds__(256)
gather_cast_kernel(const float* __restrict__ x,
                   const int* __restrict__ idx,
                   __hip_bfloat16* __restrict__ xs) {
    __shared__ float row[IN_DIM];
    const int n = blockIdx.x;
    const float* xrow = x + (size_t)n * IN_DIM;
    #pragma unroll
    for (int i = 0; i < 4; ++i) {
        const int c = (i * 256 + threadIdx.x) * 4;
        *(float4*)&row[c] = *(const float4*)&xrow[c];
    }
    __syncthreads();
    const int c0 = threadIdx.x * 8;
    int4 i0 = *(const int4*)(idx + c0);
    int4 i1 = *(const int4*)(idx + c0 + 4);
    union { bf16x8_t v; __hip_bfloat16 h[8]; } u;
    u.h[0] = __float2bfloat16(row[i0.x]);
    u.h[1] = __float2bfloat16(row[i0.y]);
    u.h[2] = __float2bfloat16(row[i0.z]);
    u.h[3] = __float2bfloat16(row[i0.w]);
    u.h[4] = __float2bfloat16(row[i1.x]);
    u.h[5] = __float2bfloat16(row[i1.y]);
    u.h[6] = __float2bfloat16(row[i1.z]);
    u.h[7] = __float2bfloat16(row[i1.w]);
    *(bf16x8_t*)(xs + (size_t)n * K_DIM + c0) = u.v;
}

__global__ void __launch_bounds__(256, 2)
gemm_fallback_kernel(const __hip_bfloat16* __restrict__ A,
                     const __hip_bfloat16* __restrict__ B,
                     const float* __restrict__ bias,
                     const int* __restrict__ oidx,
                     float* __restrict__ out)
{
    __shared__ __hip_bfloat16 As[128 * 64];
    __shared__ __hip_bfloat16 Bs[128 * 64];

    const int tid  = threadIdx.x;
    const int wave = tid >> 6;
    const int lane = tid & 63;
    const int m0 = blockIdx.y * 128;
    const int n0 = blockIdx.x * 128;

    const int wm = (wave >> 1) * 64;
    const int wn = (wave & 1) * 64;

    const int srow  = tid >> 3;
    const int sslot = tid & 7;

    const int r15 = lane & 15;
    const int qd  = lane >> 4;

    f32x4_t acc[4][4] = {};

    for (int k0 = 0; k0 < K_DIM; k0 += 64) {
        #pragma unroll
        for (int it = 0; it < 4; ++it) {
            const int row = it * 32 + srow;
            const int q = sslot ^ (row & 7);
            const __hip_bfloat16* ga = A + (size_t)(m0 + row) * K_DIM + k0 + q * 8;
            const __hip_bfloat16* gb = B + (size_t)(n0 + row) * K_DIM + k0 + q * 8;
            load_lds16(ga, (void*)&As[(it * 32 + wave * 8) * 64]);
            load_lds16(gb, (void*)&Bs[(it * 32 + wave * 8) * 64]);
        }
        __syncthreads();

        #pragma unroll
        for (int s = 0; s < 2; ++s) {
            bf16x8_t af[4], bfr[4];
            #pragma unroll
            for (int i = 0; i < 4; ++i) {
                const int rowa = wm + i * 16 + r15;
                const int pa = (s * 4 + qd) ^ (rowa & 7);
                af[i] = *(const bf16x8_t*)&As[rowa * 64 + pa * 8];
                const int rowb = wn + i * 16 + r15;
                const int pb = (s * 4 + qd) ^ (rowb & 7);
                bfr[i] = *(const bf16x8_t*)&Bs[rowb * 64 + pb * 8];
            }
            #pragma unroll
            for (int i = 0; i < 4; ++i)
                #pragma unroll
                for (int j = 0; j < 4; ++j)
                    acc[i][j] = __builtin_amdgcn_mfma_f32_16x16x32_bf16(
                        af[i], bfr[j], acc[i][j], 0, 0, 0);
        }
        __syncthreads();
    }

    #pragma unroll
    for (int j = 0; j < 4; ++j) {
        const int gn = n0 + wn + j * 16 + r15;
        const float bv = bias[gn];
        const int oc = oidx[gn];
        #pragma unroll
        for (int i = 0; i < 4; ++i) {
            const int gm = m0 + wm + i * 16 + qd * 4;
            #pragma unroll
            for (int r = 0; r < 4; ++r)
                out[(size_t)(gm + r) * OUT_DIM + oc] = acc[i][j][r] + bv;
        }
    }
}

// ---------------------------------------------------------------------------
extern "C" void kernel_launch(void* const* d_in, const int* in_sizes, int n_in,
                              void* d_out, int out_size, void* d_ws, size_t ws_size,
                              hipStream_t stream) {
    const float* x      = (const float*)d_in[0];   // [2,4096,4096]
    const float* W_base = (const float*)d_in[1];   // [2048,2048]
    const float* b_base = (const float*)d_in[2];   // [2048]
    const float* lora_A = (const float*)d_in[3];   // [16,2048]
    const float* lora_B = (const float*)d_in[4];   // [2048,16]
    const int* in_idx   = (const int*)d_in[5];     // [2048]
    const int* out_idx  = (const int*)d_in[6];     // [2048]
    float* out = (float*)d_out;                    // [8192,4096]

    const size_t sz_xs = (size_t)M_DIM * K_DIM * 2;   // 32 MB
    const size_t sz_We = (size_t)N_DIM * K_DIM * 2;   //  8 MB
    const size_t sz_C  = (size_t)M_DIM * N_DIM * 2;   // 32 MB
    const size_t sz_inv = (size_t)OUT_DIM * 4;        // 16 KB

    __hip_bfloat16* xs = (__hip_bfloat16*)d_ws;
    __hip_bfloat16* We = (__hip_bfloat16*)((char*)d_ws + sz_xs);
    __hip_bfloat16* Cc = (__hip_bfloat16*)((char*)d_ws + sz_xs + sz_We);
    int* inv           = (int*)((char*)d_ws + sz_xs + sz_We + sz_C);

    if (ws_size >= sz_xs + sz_We + sz_C + sz_inv) {
        // Single cooperative dispatch: fold + inv + gather | GEMM | expand.
        void* args[] = {
            (void*)&x, (void*)&W_base, (void*)&b_base, (void*)&lora_A,
            (void*)&lora_B, (void*)&in_idx, (void*)&out_idx,
            (void*)&xs, (void*)&We, (void*)&Cc, (void*)&inv, (void*)&out
        };
        hipLaunchCooperativeKernel((const void*)mega_kernel,
                                   dim3(N_DIM / 256, M_DIM / 256), dim3(512),
                                   args, 0, stream);
    } else {
        // Fallback: separate kernels, memset + scattered epilogue.
        fold_w_kernel<<<dim3(K_DIM / 256, N_DIM), 256, 0, stream>>>(
            W_base, lora_A, lora_B, We);
        gather_cast_kernel<<<M_DIM, 256, 0, stream>>>(x, in_idx, xs);
        hipMemsetAsync(d_out, 0, (size_t)M_DIM * OUT_DIM * sizeof(float), stream);
        gemm_fallback_kernel<<<dim3(N_DIM / 128, M_DIM / 128), 256, 0, stream>>>(
            xs, We, b_base, out_idx, out);
    }
}

// Round 4
// 438.029 us; speedup vs baseline: 1.0180x; 1.0180x over previous
//
#include <hip/hip_runtime.h>
#include <hip/hip_bf16.h>
#include <stdint.h>

// Problem constants
#define M_DIM 8192      // 2*4096 flattened batch
#define K_DIM 2048      // ACTIVE (in)
#define N_DIM 2048      // ACTIVE (out)
#define IN_DIM 4096     // ORIG_IN
#define OUT_DIM 4096    // ORIG_OUT
#define SCALING 2.0f    // 32/16

typedef __attribute__((ext_vector_type(8))) short bf16x8_t;  // 8 bf16 = 4 VGPRs
typedef __attribute__((ext_vector_type(4))) float f32x4_t;

__device__ __forceinline__ void load_lds16(const void* gptr, void* lptr) {
    __builtin_amdgcn_global_load_lds(
        (const __attribute__((address_space(1))) uint32_t*)(uintptr_t)gptr,
        (__attribute__((address_space(3))) uint32_t*)(uintptr_t)lptr,
        16, 0, 0);
}

// LDS fragment read with chunk-XOR de-swizzle (matches stage_call's source
// swizzle): p = qd ^ ((row>>1)&3), 64 B row pitch.
__device__ __forceinline__ bf16x8_t frag_ld(const __hip_bfloat16* buf, int row, int qd) {
    const int p = qd ^ ((row >> 1) & 3);
    return *(const bf16x8_t*)(buf + row * 32 + p * 8);
}

// Stage one 8 KB region: 128 rows x 32 bf16 cols, 512 threads x 16B.
// LDS dest linear (wave-uniform base); chunk swizzle applied to the GLOBAL
// source address (both-sides-or-neither rule).
__device__ __forceinline__ void stage_call(const __hip_bfloat16* __restrict__ G,
                                           int grow0,               // global row of region start
                                           __hip_bfloat16* region,  // LDS tile base (row 0)
                                           int lrow0,               // region start row in tile (0/128)
                                           int w, int l, int k0) {
    const int rr   = w * 16 + (l >> 2);        // row within region 0..127
    const int lrow = lrow0 + rr;               // row within 256-row tile (swizzle key)
    const int kc   = (l & 3) ^ ((lrow >> 1) & 3);
    load_lds16(G + (size_t)(grow0 + rr) * K_DIM + k0 + kc * 8,
               (void*)(region + (size_t)(lrow0 + w * 16) * 32));  // wave-uniform
}

// ---------------------------------------------------------------------------
// Kernel P: fused prep.  1-D grid, block-range partitioned:
//   [0, 8192)            gather+cast one x-row each (round-0 proven body)
//   [8192, 8192+2048)    fold LoRA into one W-row each
//   [10240, 10240+16)    inverse index map (binary search)
// ---------------------------------------------------------------------------
__global__ void __launch_bounds__(256)
prep_kernel(const float* __restrict__ x,
            const float* __restrict__ Wb,
            const float* __restrict__ lA,
            const float* __restrict__ lB,
            const int* __restrict__ idx,
            const int* __restrict__ oidx,
            __hip_bfloat16* __restrict__ xs,
            __hip_bfloat16* __restrict__ We,
            int* __restrict__ inv) {
    __shared__ float row[IN_DIM];
    const int bid = blockIdx.x;
    const int tid = threadIdx.x;

    if (bid < M_DIM) {
        // ---- gather active input columns + cast bf16 (LDS staging) ----
        const float* xrow = x + (size_t)bid * IN_DIM;
        #pragma unroll
        for (int i = 0; i < 4; ++i) {
            const int c = (i * 256 + tid) * 4;
            *(float4*)&row[c] = *(const float4*)&xrow[c];
        }
        __syncthreads();
        const int c0 = tid * 8;
        int4 i0 = *(const int4*)(idx + c0);
        int4 i1 = *(const int4*)(idx + c0 + 4);
        union { bf16x8_t v; __hip_bfloat16 h[8]; } u;
        u.h[0] = __float2bfloat16(row[i0.x]);
        u.h[1] = __float2bfloat16(row[i0.y]);
        u.h[2] = __float2bfloat16(row[i0.z]);
        u.h[3] = __float2bfloat16(row[i0.w]);
        u.h[4] = __float2bfloat16(row[i1.x]);
        u.h[5] = __float2bfloat16(row[i1.y]);
        u.h[6] = __float2bfloat16(row[i1.z]);
        u.h[7] = __float2bfloat16(row[i1.w]);
        *(bf16x8_t*)(xs + (size_t)bid * K_DIM + c0) = u.v;
    } else if (bid < M_DIM + N_DIM) {
        // ---- fold LoRA into base weight row, cast bf16 ----
        const int o = bid - M_DIM;
        #pragma unroll
        for (int kk = 0; kk < 8; ++kk) {
            const int k = kk * 256 + tid;
            float acc = Wb[(size_t)o * K_DIM + k];
            #pragma unroll
            for (int r = 0; r < 16; ++r)
                acc += SCALING * lB[o * 16 + r] * lA[r * K_DIM + k];
            We[(size_t)o * K_DIM + k] = __float2bfloat16(acc);
        }
    } else {
        // ---- inverse index map: inv[c] = pos of c in oidx, else -1 ----
        const int c = (bid - M_DIM - N_DIM) * 256 + tid;   // 0..4095
        int lo = 0, hi = N_DIM;
        while (lo < hi) {
            const int mid = (lo + hi) >> 1;
            if (oidx[mid] < c) lo = mid + 1; else hi = mid;
        }
        inv[c] = (lo < N_DIM && oidx[lo] == c) ? lo : -1;
    }
}

// ---------------------------------------------------------------------------
// Kernel G: 256x256-tile GEMM (round-2 K-loop, byte-identical math) with the
// output expand FUSED into the epilogue.  No compact-C round-trip:
// acc(+bias) is staged to LDS as f32 in 4 passes of 64 rows, then all 8
// waves write the block's contiguous out-column range [lo,hi) directly —
// values where inv[g] >= 0, zeros elsewhere.  Since oidx is sorted, the
// per-bx ranges [oidx[bx*256], oidx[(bx+1)*256]) tile [0,4096) exactly, and
// within a range inv[g] >= 0 implies inv[g] in [n0, n0+256).
// ---------------------------------------------------------------------------
__global__ void __launch_bounds__(512, 1)
gemm_out_kernel(const __hip_bfloat16* __restrict__ A,   // [M][K] = xs
                const __hip_bfloat16* __restrict__ B,   // [N][K] = W_eff
                const float* __restrict__ bias,         // [N]
                const int* __restrict__ oidx,           // [N] sorted
                const int* __restrict__ inv,            // [OUT_DIM]
                float* __restrict__ out)                // [M][OUT_DIM]
{
    __shared__ char smem[131072];                       // 128 KiB, phase-reused
    typedef __hip_bfloat16 ldsT;
    ldsT (*lds)[2][256 * 32] = (ldsT(*)[2][256 * 32])smem;   // [4][2][8192]

    const int tid = threadIdx.x;
    const int w   = tid >> 6;        // wave 0..7
    const int l   = tid & 63;
    const int r15 = l & 15;
    const int qd  = l >> 4;
    const int wm  = w >> 2;          // 0..1  (M half: 128 rows)
    const int wn  = w & 3;           // 0..3  (N quarter: 64 cols)
    const int bx  = blockIdx.x;
    const int m0  = blockIdx.y * 256;
    const int n0  = bx * 256;

    f32x4_t acc[8][4] = {};

    // Prologue: stage K-tiles 0,1,2 (12 vmem instrs/wave).
    #pragma unroll
    for (int t = 0; t < 3; ++t) {
        const int k0 = t * 32;
        stage_call(A, m0,       lds[t][0], 0,   w, l, k0);
        stage_call(A, m0 + 128, lds[t][0], 128, w, l, k0);
        stage_call(B, n0,       lds[t][1], 0,   w, l, k0);
        stage_call(B, n0 + 128, lds[t][1], 128, w, l, k0);
    }
    asm volatile("s_waitcnt vmcnt(8)" ::: "memory");    // tile 0 landed
    __builtin_amdgcn_sched_barrier(0);
    __builtin_amdgcn_s_barrier();

    // Main loop: 64 K-tiles of 32, quad-buffered, counted vmcnt (never 0).
    #pragma unroll 4
    for (int tt = 0; tt < 64; ++tt) {
        const int bs  = tt & 3;               // compute buffer
        const int bt  = (tt + 3) & 3;         // stage target (dead buffer)
        const int k0s = ((tt + 3) & 63) * 32;
        const __hip_bfloat16* Ab = lds[bs][0];
        const __hip_bfloat16* Bb = lds[bs][1];

        bf16x8_t af[8], bfr[4];
        #pragma unroll
        for (int i = 0; i < 8; ++i)
            af[i] = frag_ld(Ab, wm * 128 + i * 16 + r15, qd);
        #pragma unroll
        for (int j = 0; j < 4; ++j)
            bfr[j] = frag_ld(Bb, wn * 64 + j * 16 + r15, qd);

        stage_call(A, m0,       lds[bt][0], 0,   w, l, k0s);
        stage_call(A, m0 + 128, lds[bt][0], 128, w, l, k0s);
        stage_call(B, n0,       lds[bt][1], 0,   w, l, k0s);
        stage_call(B, n0 + 128, lds[bt][1], 128, w, l, k0s);

        __builtin_amdgcn_s_setprio(1);
        #pragma unroll
        for (int i = 0; i < 8; ++i)
            #pragma unroll
            for (int j = 0; j < 4; ++j)
                acc[i][j] = __builtin_amdgcn_mfma_f32_16x16x32_bf16(
                    af[i], bfr[j], acc[i][j], 0, 0, 0);
        __builtin_amdgcn_s_setprio(0);

        asm volatile("s_waitcnt vmcnt(8)" ::: "memory");
        __builtin_amdgcn_sched_barrier(0);
        __builtin_amdgcn_s_barrier();
    }
    // Drain this wave's outstanding LDS-DMA, then barrier: after this every
    // wave's DMA has landed and every wave's ds_reads are consumed -> LDS
    // is safe to reuse for the epilogue.
    asm volatile("s_waitcnt vmcnt(0)" ::: "memory");
    __syncthreads();

    // ---- fused epilogue: direct expand into out ----
    // Per-thread bias (col gn = n0 + wn*64 + j*16 + r15).
    float bv[4];
    #pragma unroll
    for (int j = 0; j < 4; ++j)
        bv[j] = bias[n0 + wn * 64 + j * 16 + r15];

    // Block's out-column range [lo, hi): tiles [0,4096) exactly across bx.
    const int lo = (bx == 0) ? 0 : oidx[bx * 256];
    const int hi = (bx == N_DIM / 256 - 1) ? OUT_DIM : oidx[(bx + 1) * 256];

    // f32 staging buffer [64][260] = 66.6 KB (stride 260: 2-way conflicts max).
    float* ldsF = (float*)smem;
    #pragma unroll 1
    for (int p = 0; p < 4; ++p) {
        // Stage rows [p*64, p*64+64) of the 256-row tile (4 owning waves).
        if (wm == (p >> 1)) {
            const int ib = (p & 1) * 4;
            #pragma unroll
            for (int ii = 0; ii < 4; ++ii)
                #pragma unroll
                for (int j = 0; j < 4; ++j)
                    #pragma unroll
                    for (int r = 0; r < 4; ++r) {
                        const int rip = ii * 16 + qd * 4 + r;      // 0..63
                        ldsF[rip * 260 + wn * 64 + j * 16 + r15] =
                            acc[ib + ii][j][r] + bv[j];
                    }
        }
        __syncthreads();
        // All 8 waves write these 64 out-rows over cols [lo, hi).
        const int Rbase = m0 + p * 64;
        for (int rr = 0; rr < 64; ++rr) {
            float* orow = out + (size_t)(Rbase + rr) * OUT_DIM;
            for (int g = lo + tid; g < hi; g += 512) {
                const int iv = inv[g];       // iv>=0 => iv in [n0, n0+256)
                orow[g] = (iv >= 0) ? ldsF[rr * 260 + (iv - n0)] : 0.0f;
            }
        }
        __syncthreads();
    }
}

// ---------------------------------------------------------------------------
// Fallback path kernels (ws too small): memset + scattered epilogue.
// ---------------------------------------------------------------------------
__global__ void __launch_bounds__(256, 2)
gemm_fallback_kernel(const __hip_bfloat16* __restrict__ A,
                     const __hip_bfloat16* __restrict__ B,
                     const float* __restrict__ bias,
                     const int* __restrict__ oidx,
                     float* __restrict__ out)
{
    __shared__ __hip_bfloat16 As[128 * 64];
    __shared__ __hip_bfloat16 Bs[128 * 64];

    const int tid  = threadIdx.x;
    const int wave = tid >> 6;
    const int lane = tid & 63;
    const int m0 = blockIdx.y * 128;
    const int n0 = blockIdx.x * 128;

    const int wm = (wave >> 1) * 64;
    const int wn = (wave & 1) * 64;

    const int srow  = tid >> 3;
    const int sslot = tid & 7;

    const int r15 = lane & 15;
    const int qd  = lane >> 4;

    f32x4_t acc[4][4] = {};

    for (int k0 = 0; k0 < K_DIM; k0 += 64) {
        #pragma unroll
        for (int it = 0; it < 4; ++it) {
            const int row = it * 32 + srow;
            const int q = sslot ^ (row & 7);
            const __hip_bfloat16* ga = A + (size_t)(m0 + row) * K_DIM + k0 + q * 8;
            const __hip_bfloat16* gb = B + (size_t)(n0 + row) * K_DIM + k0 + q * 8;
            load_lds16(ga, (void*)&As[(it * 32 + wave * 8) * 64]);
            load_lds16(gb, (void*)&Bs[(it * 32 + wave * 8) * 64]);
        }
        __syncthreads();

        #pragma unroll
        for (int s = 0; s < 2; ++s) {
            bf16x8_t af[4], bfr[4];
            #pragma unroll
            for (int i = 0; i < 4; ++i) {
                const int rowa = wm + i * 16 + r15;
                const int pa = (s * 4 + qd) ^ (rowa & 7);
                af[i] = *(const bf16x8_t*)&As[rowa * 64 + pa * 8];
                const int rowb = wn + i * 16 + r15;
                const int pb = (s * 4 + qd) ^ (rowb & 7);
                bfr[i] = *(const bf16x8_t*)&Bs[rowb * 64 + pb * 8];
            }
            #pragma unroll
            for (int i = 0; i < 4; ++i)
                #pragma unroll
                for (int j = 0; j < 4; ++j)
                    acc[i][j] = __builtin_amdgcn_mfma_f32_16x16x32_bf16(
                        af[i], bfr[j], acc[i][j], 0, 0, 0);
        }
        __syncthreads();
    }

    #pragma unroll
    for (int j = 0; j < 4; ++j) {
        const int gn = n0 + wn + j * 16 + r15;
        const float bv = bias[gn];
        const int oc = oidx[gn];
        #pragma unroll
        for (int i = 0; i < 4; ++i) {
            const int gm = m0 + wm + i * 16 + qd * 4;
            #pragma unroll
            for (int r = 0; r < 4; ++r)
                out[(size_t)(gm + r) * OUT_DIM + oc] = acc[i][j][r] + bv;
        }
    }
}

// ---------------------------------------------------------------------------
extern "C" void kernel_launch(void* const* d_in, const int* in_sizes, int n_in,
                              void* d_out, int out_size, void* d_ws, size_t ws_size,
                              hipStream_t stream) {
    const float* x      = (const float*)d_in[0];   // [2,4096,4096]
    const float* W_base = (const float*)d_in[1];   // [2048,2048]
    const float* b_base = (const float*)d_in[2];   // [2048]
    const float* lora_A = (const float*)d_in[3];   // [16,2048]
    const float* lora_B = (const float*)d_in[4];   // [2048,16]
    const int* in_idx   = (const int*)d_in[5];     // [2048]
    const int* out_idx  = (const int*)d_in[6];     // [2048]
    float* out = (float*)d_out;                    // [8192,4096]

    const size_t sz_xs  = (size_t)M_DIM * K_DIM * 2;   // 32 MB
    const size_t sz_We  = (size_t)N_DIM * K_DIM * 2;   //  8 MB
    const size_t sz_inv = (size_t)OUT_DIM * 4;         // 16 KB

    __hip_bfloat16* xs = (__hip_bfloat16*)d_ws;
    __hip_bfloat16* We = (__hip_bfloat16*)((char*)d_ws + sz_xs);
    int* inv           = (int*)((char*)d_ws + sz_xs + sz_We);

    if (ws_size >= sz_xs + sz_We + sz_inv) {
        // Two dispatches: fused prep, then GEMM with fused output expand.
        prep_kernel<<<M_DIM + N_DIM + OUT_DIM / 256, 256, 0, stream>>>(
            x, W_base, lora_A, lora_B, in_idx, out_idx, xs, We, inv);
        gemm_out_kernel<<<dim3(N_DIM / 256, M_DIM / 256), 512, 0, stream>>>(
            xs, We, b_base, out_idx, inv, out);
    } else {
        // Fallback: prep + memset + scattered-epilogue GEMM (needs 40 MB ws
        // minus inv; if even that fails, nothing works — keep prep+fallback).
        prep_kernel<<<M_DIM + N_DIM + OUT_DIM / 256, 256, 0, stream>>>(
            x, W_base, lora_A, lora_B, in_idx, out_idx, xs, We, inv);
        hipMemsetAsync(d_out, 0, (size_t)M_DIM * OUT_DIM * sizeof(float), stream);
        gemm_fallback_kernel<<<dim3(N_DIM / 128, M_DIM / 128), 256, 0, stream>>>(
            xs, We, b_base, out_idx, out);
    }
}

// Round 5
// 434.770 us; speedup vs baseline: 1.0256x; 1.0075x over previous
//
#include <hip/hip_runtime.h>
#include <hip/hip_bf16.h>
#include <stdint.h>

// Problem constants
#define M_DIM 8192      // 2*4096 flattened batch
#define K_DIM 2048      // ACTIVE (in)
#define N_DIM 2048      // ACTIVE (out)
#define IN_DIM 4096     // ORIG_IN
#define OUT_DIM 4096    // ORIG_OUT
#define SCALING 2.0f    // 32/16

typedef __attribute__((ext_vector_type(8))) short bf16x8_t;  // 8 bf16 = 4 VGPRs
typedef __attribute__((ext_vector_type(4))) float f32x4_t;

__device__ __forceinline__ void load_lds16(const void* gptr, void* lptr) {
    __builtin_amdgcn_global_load_lds(
        (const __attribute__((address_space(1))) uint32_t*)(uintptr_t)gptr,
        (__attribute__((address_space(3))) uint32_t*)(uintptr_t)lptr,
        16, 0, 0);
}

// LDS fragment read with chunk-XOR de-swizzle (matches stage_call's source
// swizzle): p = qd ^ ((row>>1)&3), 64 B row pitch.
__device__ __forceinline__ bf16x8_t frag_ld(const __hip_bfloat16* buf, int row, int qd) {
    const int p = qd ^ ((row >> 1) & 3);
    return *(const bf16x8_t*)(buf + row * 32 + p * 8);
}

// Stage one 64-row x 32-col bf16 region (4 KB) with 4 waves x 16 rows.
// LDS dest linear (wave-uniform base); chunk swizzle applied to the GLOBAL
// source address (both-sides-or-neither rule).
__device__ __forceinline__ void stage_call(const __hip_bfloat16* __restrict__ G,
                                           int grow0,               // global row of region start
                                           __hip_bfloat16* region,  // LDS tile base (row 0)
                                           int lrow0,               // region start row in tile (0/64)
                                           int w, int l, int k0) {
    const int rr   = w * 16 + (l >> 2);        // row within region 0..63
    const int lrow = lrow0 + rr;               // row within 128-row tile (swizzle key)
    const int kc   = (l & 3) ^ ((lrow >> 1) & 3);
    load_lds16(G + (size_t)(grow0 + rr) * K_DIM + k0 + kc * 8,
               (void*)(region + (size_t)(lrow0 + w * 16) * 32));  // wave-uniform
}

// ---------------------------------------------------------------------------
// Kernel P: fused prep.  1-D grid, block-range partitioned:
//   [0, 8192)            gather+cast one x-row each
//   [8192, 8192+2048)    fold LoRA into one W-row each
//   [10240, 10240+16)    inverse index map (binary search)
// ---------------------------------------------------------------------------
__global__ void __launch_bounds__(256)
prep_kernel(const float* __restrict__ x,
            const float* __restrict__ Wb,
            const float* __restrict__ lA,
            const float* __restrict__ lB,
            const int* __restrict__ idx,
            const int* __restrict__ oidx,
            __hip_bfloat16* __restrict__ xs,
            __hip_bfloat16* __restrict__ We,
            int* __restrict__ inv) {
    __shared__ float row[IN_DIM];
    const int bid = blockIdx.x;
    const int tid = threadIdx.x;

    if (bid < M_DIM) {
        // ---- gather active input columns + cast bf16 (LDS staging) ----
        const float* xrow = x + (size_t)bid * IN_DIM;
        #pragma unroll
        for (int i = 0; i < 4; ++i) {
            const int c = (i * 256 + tid) * 4;
            *(float4*)&row[c] = *(const float4*)&xrow[c];
        }
        __syncthreads();
        const int c0 = tid * 8;
        int4 i0 = *(const int4*)(idx + c0);
        int4 i1 = *(const int4*)(idx + c0 + 4);
        union { bf16x8_t v; __hip_bfloat16 h[8]; } u;
        u.h[0] = __float2bfloat16(row[i0.x]);
        u.h[1] = __float2bfloat16(row[i0.y]);
        u.h[2] = __float2bfloat16(row[i0.z]);
        u.h[3] = __float2bfloat16(row[i0.w]);
        u.h[4] = __float2bfloat16(row[i1.x]);
        u.h[5] = __float2bfloat16(row[i1.y]);
        u.h[6] = __float2bfloat16(row[i1.z]);
        u.h[7] = __float2bfloat16(row[i1.w]);
        *(bf16x8_t*)(xs + (size_t)bid * K_DIM + c0) = u.v;
    } else if (bid < M_DIM + N_DIM) {
        // ---- fold LoRA into base weight row, cast bf16 ----
        const int o = bid - M_DIM;
        #pragma unroll
        for (int kk = 0; kk < 8; ++kk) {
            const int k = kk * 256 + tid;
            float acc = Wb[(size_t)o * K_DIM + k];
            #pragma unroll
            for (int r = 0; r < 16; ++r)
                acc += SCALING * lB[o * 16 + r] * lA[r * K_DIM + k];
            We[(size_t)o * K_DIM + k] = __float2bfloat16(acc);
        }
    } else {
        // ---- inverse index map: inv[c] = pos of c in oidx, else -1 ----
        const int c = (bid - M_DIM - N_DIM) * 256 + tid;   // 0..4095
        int lo = 0, hi = N_DIM;
        while (lo < hi) {
            const int mid = (lo + hi) >> 1;
            if (oidx[mid] < c) lo = mid + 1; else hi = mid;
        }
        inv[c] = (lo < N_DIM && oidx[lo] == c) ? lo : -1;
    }
}

// ---------------------------------------------------------------------------
// Kernel G: 128x128-tile GEMM, 4 waves (2Mx2N), BK=32, QUAD-buffered LDS
// (4 x 16 KB = 64 KiB -> 2 blocks/CU, grid 1024 -> inter-block overlap),
// counted-vmcnt pipeline (same constants as round 4: stage t+3 into dead
// t-1 buffer, vmcnt(8) = 2 K-tiles always in flight).  XCD swizzle: each
// XCD gets 8 contiguous by-panels (A pinned in its 4 MB L2).  Epilogue:
// direct expand to out via 32-row LDS staging + float4 interior stores
// (scalar only at the <=3-col unaligned range edges).
// ---------------------------------------------------------------------------
__global__ void __launch_bounds__(256, 2)
gemm_out_kernel(const __hip_bfloat16* __restrict__ A,   // [M][K] = xs
                const __hip_bfloat16* __restrict__ B,   // [N][K] = W_eff
                const float* __restrict__ bias,         // [N]
                const int* __restrict__ oidx,           // [N] sorted
                const int* __restrict__ inv,            // [OUT_DIM]
                float* __restrict__ out)                // [M][OUT_DIM]
{
    __shared__ char smem[65536];                        // 64 KiB, phase-reused
    typedef __hip_bfloat16 ldsT;
    ldsT (*lds)[2][128 * 32] = (ldsT(*)[2][128 * 32])smem;   // [4][2][4096]

    const int tid = threadIdx.x;
    const int w   = tid >> 6;        // wave 0..3
    const int l   = tid & 63;
    const int r15 = l & 15;
    const int qd  = l >> 4;
    const int wm  = w >> 1;          // 0..1  (M half: 64 rows)
    const int wn  = w & 1;           // 0..1  (N half: 64 cols)

    // XCD swizzle (bijective, 1024 % 8 == 0): XCD k (dispatch round-robin,
    // blocks bid%8==k) gets swz in [k*128,(k+1)*128) -> by in [k*8,k*8+8),
    // all 16 bx.  Per-XCD L2 working set: 8 A-panels (4 MB, pinned) + B.
    const int bid = blockIdx.x;                 // 0..1023
    const int swz = (bid & 7) * 128 + (bid >> 3);
    const int bx  = swz & 15;                   // N tile 0..15
    const int by  = swz >> 4;                   // M tile 0..63
    const int m0  = by * 128;
    const int n0  = bx * 128;

    f32x4_t acc[4][4] = {};

    // Prologue: stage K-tiles 0,1,2 (12 vmem instrs/wave; 4 calls/tile).
    #pragma unroll
    for (int t = 0; t < 3; ++t) {
        const int k0 = t * 32;
        stage_call(A, m0,      lds[t][0], 0,  w, l, k0);
        stage_call(A, m0 + 64, lds[t][0], 64, w, l, k0);
        stage_call(B, n0,      lds[t][1], 0,  w, l, k0);
        stage_call(B, n0 + 64, lds[t][1], 64, w, l, k0);
    }
    asm volatile("s_waitcnt vmcnt(8)" ::: "memory");    // tile 0 landed
    __builtin_amdgcn_sched_barrier(0);
    __builtin_amdgcn_s_barrier();

    // Main loop: 64 K-tiles of 32, quad-buffered, counted vmcnt (never 0).
    #pragma unroll 4
    for (int tt = 0; tt < 64; ++tt) {
        const int bs  = tt & 3;               // compute buffer
        const int bt  = (tt + 3) & 3;         // stage target (dead buffer)
        const int k0s = ((tt + 3) & 63) * 32;
        const __hip_bfloat16* Ab = lds[bs][0];
        const __hip_bfloat16* Bb = lds[bs][1];

        bf16x8_t af[4], bfr[4];
        #pragma unroll
        for (int i = 0; i < 4; ++i)
            af[i] = frag_ld(Ab, wm * 64 + i * 16 + r15, qd);
        #pragma unroll
        for (int j = 0; j < 4; ++j)
            bfr[j] = frag_ld(Bb, wn * 64 + j * 16 + r15, qd);

        stage_call(A, m0,      lds[bt][0], 0,  w, l, k0s);
        stage_call(A, m0 + 64, lds[bt][0], 64, w, l, k0s);
        stage_call(B, n0,      lds[bt][1], 0,  w, l, k0s);
        stage_call(B, n0 + 64, lds[bt][1], 64, w, l, k0s);

        __builtin_amdgcn_s_setprio(1);
        #pragma unroll
        for (int i = 0; i < 4; ++i)
            #pragma unroll
            for (int j = 0; j < 4; ++j)
                acc[i][j] = __builtin_amdgcn_mfma_f32_16x16x32_bf16(
                    af[i], bfr[j], acc[i][j], 0, 0, 0);
        __builtin_amdgcn_s_setprio(0);

        asm volatile("s_waitcnt vmcnt(8)" ::: "memory");
        __builtin_amdgcn_sched_barrier(0);
        __builtin_amdgcn_s_barrier();
    }
    // Drain this wave's LDS-DMA; barrier -> LDS reusable for epilogue.
    asm volatile("s_waitcnt vmcnt(0)" ::: "memory");
    __syncthreads();

    // ---- fused epilogue: direct expand into out ----
    float bv[4];
    #pragma unroll
    for (int j = 0; j < 4; ++j)
        bv[j] = bias[n0 + wn * 64 + j * 16 + r15];

    // Block's out-column range [lo, hi): ranges tile [0,4096) exactly, and
    // within a range inv[g] >= 0 implies inv[g] in [n0, n0+128).
    const int lo  = (bx == 0) ? 0 : oidx[bx * 128];
    const int hi  = (bx == 15) ? OUT_DIM : oidx[(bx + 1) * 128];
    const int lo4 = (lo + 3) & ~3;
    const int hi4 = hi & ~3;

    // f32 staging [32][132] = 16.9 KB (stride 132 -> 2-way conflicts max).
    float* ldsF = (float*)smem;
    #pragma unroll 1
    for (int p = 0; p < 4; ++p) {
        // Stage tile-rows [p*32, p*32+32): the 2 waves with wm == p>>1.
        if (wm == (p >> 1)) {
            const int ib = (p & 1) * 2;
            #pragma unroll
            for (int ii = 0; ii < 2; ++ii)
                #pragma unroll
                for (int j = 0; j < 4; ++j)
                    #pragma unroll
                    for (int r = 0; r < 4; ++r) {
                        const int lr = ii * 16 + qd * 4 + r;   // 0..31
                        ldsF[lr * 132 + wn * 64 + j * 16 + r15] =
                            acc[ib + ii][j][r] + bv[j];
                    }
        }
        __syncthreads();
        // All 4 waves write these 32 out-rows (8 rows/wave) over [lo, hi).
        const int Rbase = m0 + p * 32;
        for (int rr = w * 8; rr < w * 8 + 8; ++rr) {
            float* orow = out + (size_t)(Rbase + rr) * OUT_DIM;
            const float* lrow = ldsF + rr * 132;
            // scalar edges (at most 3 cols each side)
            for (int g = lo + l; g < lo4; g += 64) {
                const int iv = inv[g];
                orow[g] = (iv >= 0) ? lrow[iv - n0] : 0.0f;
            }
            for (int g = hi4 + l; g < hi; g += 64) {
                const int iv = inv[g];
                orow[g] = (iv >= 0) ? lrow[iv - n0] : 0.0f;
            }
            // float4 interior (full-line stores)
            for (int g4 = lo4 + l * 4; g4 < hi4; g4 += 256) {
                const int4 iv4 = *(const int4*)(inv + g4);
                float4 v;
                v.x = (iv4.x >= 0) ? lrow[iv4.x - n0] : 0.0f;
                v.y = (iv4.y >= 0) ? lrow[iv4.y - n0] : 0.0f;
                v.z = (iv4.z >= 0) ? lrow[iv4.z - n0] : 0.0f;
                v.w = (iv4.w >= 0) ? lrow[iv4.w - n0] : 0.0f;
                *(float4*)(orow + g4) = v;
            }
        }
        __syncthreads();
    }
}

// ---------------------------------------------------------------------------
// Fallback path kernels (ws too small): memset + scattered epilogue.
// ---------------------------------------------------------------------------
__global__ void __launch_bounds__(256, 2)
gemm_fallback_kernel(const __hip_bfloat16* __restrict__ A,
                     const __hip_bfloat16* __restrict__ B,
                     const float* __restrict__ bias,
                     const int* __restrict__ oidx,
                     float* __restrict__ out)
{
    __shared__ __hip_bfloat16 As[128 * 64];
    __shared__ __hip_bfloat16 Bs[128 * 64];

    const int tid  = threadIdx.x;
    const int wave = tid >> 6;
    const int lane = tid & 63;
    const int m0 = blockIdx.y * 128;
    const int n0 = blockIdx.x * 128;

    const int wm = (wave >> 1) * 64;
    const int wn = (wave & 1) * 64;

    const int srow  = tid >> 3;
    const int sslot = tid & 7;

    const int r15 = lane & 15;
    const int qd  = lane >> 4;

    f32x4_t acc[4][4] = {};

    for (int k0 = 0; k0 < K_DIM; k0 += 64) {
        #pragma unroll
        for (int it = 0; it < 4; ++it) {
            const int row = it * 32 + srow;
            const int q = sslot ^ (row & 7);
            const __hip_bfloat16* ga = A + (size_t)(m0 + row) * K_DIM + k0 + q * 8;
            const __hip_bfloat16* gb = B + (size_t)(n0 + row) * K_DIM + k0 + q * 8;
            load_lds16(ga, (void*)&As[(it * 32 + wave * 8) * 64]);
            load_lds16(gb, (void*)&Bs[(it * 32 + wave * 8) * 64]);
        }
        __syncthreads();

        #pragma unroll
        for (int s = 0; s < 2; ++s) {
            bf16x8_t af[4], bfr[4];
            #pragma unroll
            for (int i = 0; i < 4; ++i) {
                const int rowa = wm + i * 16 + r15;
                const int pa = (s * 4 + qd) ^ (rowa & 7);
                af[i] = *(const bf16x8_t*)&As[rowa * 64 + pa * 8];
                const int rowb = wn + i * 16 + r15;
                const int pb = (s * 4 + qd) ^ (rowb & 7);
                bfr[i] = *(const bf16x8_t*)&Bs[rowb * 64 + pb * 8];
            }
            #pragma unroll
            for (int i = 0; i < 4; ++i)
                #pragma unroll
                for (int j = 0; j < 4; ++j)
                    acc[i][j] = __builtin_amdgcn_mfma_f32_16x16x32_bf16(
                        af[i], bfr[j], acc[i][j], 0, 0, 0);
        }
        __syncthreads();
    }

    #pragma unroll
    for (int j = 0; j < 4; ++j) {
        const int gn = n0 + wn + j * 16 + r15;
        const float bv = bias[gn];
        const int oc = oidx[gn];
        #pragma unroll
        for (int i = 0; i < 4; ++i) {
            const int gm = m0 + wm + i * 16 + qd * 4;
            #pragma unroll
            for (int r = 0; r < 4; ++r)
                out[(size_t)(gm + r) * OUT_DIM + oc] = acc[i][j][r] + bv;
        }
    }
}

// ---------------------------------------------------------------------------
extern "C" void kernel_launch(void* const* d_in, const int* in_sizes, int n_in,
                              void* d_out, int out_size, void* d_ws, size_t ws_size,
                              hipStream_t stream) {
    const float* x      = (const float*)d_in[0];   // [2,4096,4096]
    const float* W_base = (const float*)d_in[1];   // [2048,2048]
    const float* b_base = (const float*)d_in[2];   // [2048]
    const float* lora_A = (const float*)d_in[3];   // [16,2048]
    const float* lora_B = (const float*)d_in[4];   // [2048,16]
    const int* in_idx   = (const int*)d_in[5];     // [2048]
    const int* out_idx  = (const int*)d_in[6];     // [2048]
    float* out = (float*)d_out;                    // [8192,4096]

    const size_t sz_xs  = (size_t)M_DIM * K_DIM * 2;   // 32 MB
    const size_t sz_We  = (size_t)N_DIM * K_DIM * 2;   //  8 MB
    const size_t sz_inv = (size_t)OUT_DIM * 4;         // 16 KB

    __hip_bfloat16* xs = (__hip_bfloat16*)d_ws;
    __hip_bfloat16* We = (__hip_bfloat16*)((char*)d_ws + sz_xs);
    int* inv           = (int*)((char*)d_ws + sz_xs + sz_We);

    if (ws_size >= sz_xs + sz_We + sz_inv) {
        // Two dispatches: fused prep, then GEMM with fused output expand.
        prep_kernel<<<M_DIM + N_DIM + OUT_DIM / 256, 256, 0, stream>>>(
            x, W_base, lora_A, lora_B, in_idx, out_idx, xs, We, inv);
        gemm_out_kernel<<<(M_DIM / 128) * (N_DIM / 128), 256, 0, stream>>>(
            xs, We, b_base, out_idx, inv, out);
    } else {
        // Fallback: prep + memset + scattered-epilogue GEMM.
        prep_kernel<<<M_DIM + N_DIM + OUT_DIM / 256, 256, 0, stream>>>(
            x, W_base, lora_A, lora_B, in_idx, out_idx, xs, We, inv);
        hipMemsetAsync(d_out, 0, (size_t)M_DIM * OUT_DIM * sizeof(float), stream);
        gemm_fallback_kernel<<<dim3(N_DIM / 128, M_DIM / 128), 256, 0, stream>>>(
            xs, We, b_base, out_idx, out);
    }
}

// Round 6
// 350.386 us; speedup vs baseline: 1.2726x; 1.2408x over previous
//
#include <hip/hip_runtime.h>
#include <hip/hip_bf16.h>
#include <stdint.h>

// Problem constants
#define M_DIM 8192      // 2*4096 flattened batch
#define K_DIM 2048      // ACTIVE (in)
#define N_DIM 2048      // ACTIVE (out)
#define IN_DIM 4096     // ORIG_IN
#define OUT_DIM 4096    // ORIG_OUT
#define SCALING 2.0f    // 32/16

typedef __attribute__((ext_vector_type(8))) short bf16x8_t;  // 8 bf16 = 4 VGPRs
typedef __attribute__((ext_vector_type(4))) float f32x4_t;

__device__ __forceinline__ void load_lds16(const void* gptr, void* lptr) {
    __builtin_amdgcn_global_load_lds(
        (const __attribute__((address_space(1))) uint32_t*)(uintptr_t)gptr,
        (__attribute__((address_space(3))) uint32_t*)(uintptr_t)lptr,
        16, 0, 0);
}

// LDS fragment read with chunk-XOR de-swizzle (matches stage_call's source
// swizzle): p = qd ^ ((row>>1)&3), 64 B row pitch.
__device__ __forceinline__ bf16x8_t frag_ld(const __hip_bfloat16* buf, int row, int qd) {
    const int p = qd ^ ((row >> 1) & 3);
    return *(const bf16x8_t*)(buf + row * 32 + p * 8);
}

// Stage one 8 KB region: 128 rows x 32 bf16 cols, 512 threads x 16B.
// LDS dest linear (wave-uniform base); chunk swizzle applied to the GLOBAL
// source address (both-sides-or-neither rule).
__device__ __forceinline__ void stage_call(const __hip_bfloat16* __restrict__ G,
                                           int grow0,               // global row of region start
                                           __hip_bfloat16* region,  // LDS tile base (row 0)
                                           int lrow0,               // region start row in tile (0/128)
                                           int w, int l, int k0) {
    const int rr   = w * 16 + (l >> 2);        // row within region 0..127
    const int lrow = lrow0 + rr;               // row within 256-row tile (swizzle key)
    const int kc   = (l & 3) ^ ((lrow >> 1) & 3);
    load_lds16(G + (size_t)(grow0 + rr) * K_DIM + k0 + kc * 8,
               (void*)(region + (size_t)(lrow0 + w * 16) * 32));  // wave-uniform
}

// ---------------------------------------------------------------------------
// Kernel P: fused prep (proven rounds 4-5).  1-D grid, block-partitioned:
//   [0, 8192)            gather+cast one x-row each
//   [8192, 10240)        fold LoRA into one W-row each
//   [10240, 10256)       inverse index map (binary search)
// ---------------------------------------------------------------------------
__global__ void __launch_bounds__(256)
prep_kernel(const float* __restrict__ x,
            const float* __restrict__ Wb,
            const float* __restrict__ lA,
            const float* __restrict__ lB,
            const int* __restrict__ idx,
            const int* __restrict__ oidx,
            __hip_bfloat16* __restrict__ xs,
            __hip_bfloat16* __restrict__ We,
            int* __restrict__ inv) {
    __shared__ float row[IN_DIM];
    const int bid = blockIdx.x;
    const int tid = threadIdx.x;

    if (bid < M_DIM) {
        // ---- gather active input columns + cast bf16 (LDS staging) ----
        const float* xrow = x + (size_t)bid * IN_DIM;
        #pragma unroll
        for (int i = 0; i < 4; ++i) {
            const int c = (i * 256 + tid) * 4;
            *(float4*)&row[c] = *(const float4*)&xrow[c];
        }
        __syncthreads();
        const int c0 = tid * 8;
        int4 i0 = *(const int4*)(idx + c0);
        int4 i1 = *(const int4*)(idx + c0 + 4);
        union { bf16x8_t v; __hip_bfloat16 h[8]; } u;
        u.h[0] = __float2bfloat16(row[i0.x]);
        u.h[1] = __float2bfloat16(row[i0.y]);
        u.h[2] = __float2bfloat16(row[i0.z]);
        u.h[3] = __float2bfloat16(row[i0.w]);
        u.h[4] = __float2bfloat16(row[i1.x]);
        u.h[5] = __float2bfloat16(row[i1.y]);
        u.h[6] = __float2bfloat16(row[i1.z]);
        u.h[7] = __float2bfloat16(row[i1.w]);
        *(bf16x8_t*)(xs + (size_t)bid * K_DIM + c0) = u.v;
    } else if (bid < M_DIM + N_DIM) {
        // ---- fold LoRA into base weight row, cast bf16 ----
        const int o = bid - M_DIM;
        #pragma unroll
        for (int kk = 0; kk < 8; ++kk) {
            const int k = kk * 256 + tid;
            float acc = Wb[(size_t)o * K_DIM + k];
            #pragma unroll
            for (int r = 0; r < 16; ++r)
                acc += SCALING * lB[o * 16 + r] * lA[r * K_DIM + k];
            We[(size_t)o * K_DIM + k] = __float2bfloat16(acc);
        }
    } else {
        // ---- inverse index map: inv[c] = pos of c in oidx, else -1 ----
        const int c = (bid - M_DIM - N_DIM) * 256 + tid;   // 0..4095
        int lo = 0, hi = N_DIM;
        while (lo < hi) {
            const int mid = (lo + hi) >> 1;
            if (oidx[mid] < c) lo = mid + 1; else hi = mid;
        }
        inv[c] = (lo < N_DIM && oidx[lo] == c) ? lo : -1;
    }
}

// ---------------------------------------------------------------------------
// Kernel G: 256x256 tile GEMM -> compact bf16 C (round-2 body, verbatim).
// 8 waves (2Mx4N), BK=32, quad-buffered LDS (128 KiB), counted-vmcnt
// pipeline: stage tile t+3 into the dead t-1 buffer, vmcnt(8) keeps 2
// K-tiles in flight across the single per-tile barrier.
// ---------------------------------------------------------------------------
__global__ void __launch_bounds__(512, 1)
gemm256_kernel(const __hip_bfloat16* __restrict__ A,   // [M][K] = xs
               const __hip_bfloat16* __restrict__ B,   // [N][K] = W_eff
               const float* __restrict__ bias,         // [N]
               __hip_bfloat16* __restrict__ Cc)        // [M][N] compact
{
    __shared__ __hip_bfloat16 lds[4][2][256 * 32];     // [buf][A=0/B=1] 128 KiB

    const int tid = threadIdx.x;
    const int w   = tid >> 6;        // wave 0..7
    const int l   = tid & 63;
    const int r15 = l & 15;
    const int qd  = l >> 4;
    const int wm  = w >> 2;          // 0..1  (M half: 128 rows)
    const int wn  = w & 3;           // 0..3  (N quarter: 64 cols)
    const int m0  = blockIdx.y * 256;
    const int n0  = blockIdx.x * 256;

    f32x4_t acc[8][4] = {};

    // Prologue: stage K-tiles 0,1,2 (12 vmem instrs/wave).
    #pragma unroll
    for (int t = 0; t < 3; ++t) {
        const int k0 = t * 32;
        stage_call(A, m0,       lds[t][0], 0,   w, l, k0);
        stage_call(A, m0 + 128, lds[t][0], 128, w, l, k0);
        stage_call(B, n0,       lds[t][1], 0,   w, l, k0);
        stage_call(B, n0 + 128, lds[t][1], 128, w, l, k0);
    }
    asm volatile("s_waitcnt vmcnt(8)" ::: "memory");   // tile 0 landed; 1,2 in flight
    __builtin_amdgcn_sched_barrier(0);
    __builtin_amdgcn_s_barrier();

    // Main loop: 64 K-tiles of 32.  Stage index wraps (garbage re-stages into
    // dead, never-again-read buffers for tt+3 >= 64) so vmcnt stays uniform.
    #pragma unroll 4
    for (int tt = 0; tt < 64; ++tt) {
        const int bs  = tt & 3;               // compute buffer
        const int bt  = (tt + 3) & 3;         // stage target = dead t-1 buffer
        const int k0s = ((tt + 3) & 63) * 32;
        const __hip_bfloat16* Ab = lds[bs][0];
        const __hip_bfloat16* Bb = lds[bs][1];

        // Issue ALL fragment loads for this K-tile (16 x ds_read_b128).
        bf16x8_t af[8], bfr[4];
        #pragma unroll
        for (int i = 0; i < 8; ++i)
            af[i] = frag_ld(Ab, wm * 128 + i * 16 + r15, qd);
        #pragma unroll
        for (int j = 0; j < 4; ++j)
            bfr[j] = frag_ld(Bb, wn * 64 + j * 16 + r15, qd);

        // Stage K-tile tt+3 into the dead buffer (4 x global_load_lds).
        stage_call(A, m0,       lds[bt][0], 0,   w, l, k0s);
        stage_call(A, m0 + 128, lds[bt][0], 128, w, l, k0s);
        stage_call(B, n0,       lds[bt][1], 0,   w, l, k0s);
        stage_call(B, n0 + 128, lds[bt][1], 128, w, l, k0s);

        // 32 MFMAs; compiler interleaves ds_read waits (fine-grained lgkmcnt).
        __builtin_amdgcn_s_setprio(1);
        #pragma unroll
        for (int i = 0; i < 8; ++i)
            #pragma unroll
            for (int j = 0; j < 4; ++j)
                acc[i][j] = __builtin_amdgcn_mfma_f32_16x16x32_bf16(
                    af[i], bfr[j], acc[i][j], 0, 0, 0);
        __builtin_amdgcn_s_setprio(0);

        // Counted wait: 8 stage instrs (tiles tt+2, tt+3) stay in flight.
        asm volatile("s_waitcnt vmcnt(8)" ::: "memory");
        __builtin_amdgcn_sched_barrier(0);
        __builtin_amdgcn_s_barrier();
    }
    // Drain outstanding LDS-DMA before LDS goes out of scope.
    asm volatile("s_waitcnt vmcnt(0)" ::: "memory");

    // Epilogue: C/D layout (verified m89/m91): col = lane&15, row = qd*4 + reg
    #pragma unroll
    for (int j = 0; j < 4; ++j) {
        const int gn = n0 + wn * 64 + j * 16 + r15;
        const float bv = bias[gn];
        #pragma unroll
        for (int i = 0; i < 8; ++i) {
            const int gm = m0 + wm * 128 + i * 16 + qd * 4;
            #pragma unroll
            for (int r = 0; r < 4; ++r)
                Cc[(size_t)(gm + r) * N_DIM + gn] =
                    __float2bfloat16(acc[i][j][r] + bv);
        }
    }
}

// ---------------------------------------------------------------------------
// Kernel S: expand compact C into full output (round-0 body, verbatim).
// Fully coalesced float4 writes; replaces any memset.
// ---------------------------------------------------------------------------
__global__ void __launch_bounds__(256)
scatter_out_kernel(const __hip_bfloat16* __restrict__ C,   // [M][N]
                   const int* __restrict__ inv,            // [OUT_DIM]
                   float* __restrict__ out) {              // [M][OUT_DIM]
    const int row = blockIdx.y;
    const int c0 = (blockIdx.x * 256 + threadIdx.x) * 4;
    const __hip_bfloat16* crow = C + (size_t)row * N_DIM;
    const int4 iv = *(const int4*)(inv + c0);
    float4 v;
    v.x = (iv.x >= 0) ? __bfloat162float(crow[iv.x]) : 0.0f;
    v.y = (iv.y >= 0) ? __bfloat162float(crow[iv.y]) : 0.0f;
    v.z = (iv.z >= 0) ? __bfloat162float(crow[iv.z]) : 0.0f;
    v.w = (iv.w >= 0) ? __bfloat162float(crow[iv.w]) : 0.0f;
    *(float4*)(out + (size_t)row * OUT_DIM + c0) = v;
}

// ---------------------------------------------------------------------------
// Fallback GEMM (ws too small): memset + scattered epilogue.
// ---------------------------------------------------------------------------
__global__ void __launch_bounds__(256, 2)
gemm_fallback_kernel(const __hip_bfloat16* __restrict__ A,
                     const __hip_bfloat16* __restrict__ B,
                     const float* __restrict__ bias,
                     const int* __restrict__ oidx,
                     float* __restrict__ out)
{
    __shared__ __hip_bfloat16 As[128 * 64];
    __shared__ __hip_bfloat16 Bs[128 * 64];

    const int tid  = threadIdx.x;
    const int wave = tid >> 6;
    const int lane = tid & 63;
    const int m0 = blockIdx.y * 128;
    const int n0 = blockIdx.x * 128;

    const int wm = (wave >> 1) * 64;
    const int wn = (wave & 1) * 64;

    const int srow  = tid >> 3;
    const int sslot = tid & 7;

    const int r15 = lane & 15;
    const int qd  = lane >> 4;

    f32x4_t acc[4][4] = {};

    for (int k0 = 0; k0 < K_DIM; k0 += 64) {
        #pragma unroll
        for (int it = 0; it < 4; ++it) {
            const int row = it * 32 + srow;
            const int q = sslot ^ (row & 7);
            const __hip_bfloat16* ga = A + (size_t)(m0 + row) * K_DIM + k0 + q * 8;
            const __hip_bfloat16* gb = B + (size_t)(n0 + row) * K_DIM + k0 + q * 8;
            load_lds16(ga, (void*)&As[(it * 32 + wave * 8) * 64]);
            load_lds16(gb, (void*)&Bs[(it * 32 + wave * 8) * 64]);
        }
        __syncthreads();

        #pragma unroll
        for (int s = 0; s < 2; ++s) {
            bf16x8_t af[4], bfr[4];
            #pragma unroll
            for (int i = 0; i < 4; ++i) {
                const int rowa = wm + i * 16 + r15;
                const int pa = (s * 4 + qd) ^ (rowa & 7);
                af[i] = *(const bf16x8_t*)&As[rowa * 64 + pa * 8];
                const int rowb = wn + i * 16 + r15;
                const int pb = (s * 4 + qd) ^ (rowb & 7);
                bfr[i] = *(const bf16x8_t*)&Bs[rowb * 64 + pb * 8];
            }
            #pragma unroll
            for (int i = 0; i < 4; ++i)
                #pragma unroll
                for (int j = 0; j < 4; ++j)
                    acc[i][j] = __builtin_amdgcn_mfma_f32_16x16x32_bf16(
                        af[i], bfr[j], acc[i][j], 0, 0, 0);
        }
        __syncthreads();
    }

    #pragma unroll
    for (int j = 0; j < 4; ++j) {
        const int gn = n0 + wn + j * 16 + r15;
        const float bv = bias[gn];
        const int oc = oidx[gn];
        #pragma unroll
        for (int i = 0; i < 4; ++i) {
            const int gm = m0 + wm + i * 16 + qd * 4;
            #pragma unroll
            for (int r = 0; r < 4; ++r)
                out[(size_t)(gm + r) * OUT_DIM + oc] = acc[i][j][r] + bv;
        }
    }
}

// ---------------------------------------------------------------------------
extern "C" void kernel_launch(void* const* d_in, const int* in_sizes, int n_in,
                              void* d_out, int out_size, void* d_ws, size_t ws_size,
                              hipStream_t stream) {
    const float* x      = (const float*)d_in[0];   // [2,4096,4096]
    const float* W_base = (const float*)d_in[1];   // [2048,2048]
    const float* b_base = (const float*)d_in[2];   // [2048]
    const float* lora_A = (const float*)d_in[3];   // [16,2048]
    const float* lora_B = (const float*)d_in[4];   // [2048,16]
    const int* in_idx   = (const int*)d_in[5];     // [2048]
    const int* out_idx  = (const int*)d_in[6];     // [2048]
    float* out = (float*)d_out;                    // [8192,4096]

    const size_t sz_xs  = (size_t)M_DIM * K_DIM * 2;   // 32 MB
    const size_t sz_We  = (size_t)N_DIM * K_DIM * 2;   //  8 MB
    const size_t sz_C   = (size_t)M_DIM * N_DIM * 2;   // 32 MB
    const size_t sz_inv = (size_t)OUT_DIM * 4;         // 16 KB

    __hip_bfloat16* xs = (__hip_bfloat16*)d_ws;
    __hip_bfloat16* We = (__hip_bfloat16*)((char*)d_ws + sz_xs);
    __hip_bfloat16* Cc = (__hip_bfloat16*)((char*)d_ws + sz_xs + sz_We);
    int* inv           = (int*)((char*)d_ws + sz_xs + sz_We + sz_C);

    if (ws_size >= sz_xs + sz_We + sz_C + sz_inv) {
        // Three dispatches: fused prep -> 256^2 GEMM -> coalesced expand.
        prep_kernel<<<M_DIM + N_DIM + OUT_DIM / 256, 256, 0, stream>>>(
            x, W_base, lora_A, lora_B, in_idx, out_idx, xs, We, inv);
        gemm256_kernel<<<dim3(N_DIM / 256, M_DIM / 256), 512, 0, stream>>>(
            xs, We, b_base, Cc);
        scatter_out_kernel<<<dim3(OUT_DIM / (256 * 4), M_DIM), 256, 0, stream>>>(
            Cc, inv, out);
    } else {
        // Fallback: prep + memset + scattered-epilogue GEMM.
        prep_kernel<<<M_DIM + N_DIM + OUT_DIM / 256, 256, 0, stream>>>(
            x, W_base, lora_A, lora_B, in_idx, out_idx, xs, We, inv);
        hipMemsetAsync(d_out, 0, (size_t)M_DIM * OUT_DIM * sizeof(float), stream);
        gemm_fallback_kernel<<<dim3(N_DIM / 128, M_DIM / 128), 256, 0, stream>>>(
            xs, We, b_base, out_idx, out);
    }
}

// Round 7
// 349.351 us; speedup vs baseline: 1.2764x; 1.0030x over previous
//
#include <hip/hip_runtime.h>
#include <hip/hip_bf16.h>
#include <stdint.h>

// Problem constants
#define M_DIM 8192      // 2*4096 flattened batch
#define K_DIM 2048      // ACTIVE (in)
#define N_DIM 2048      // ACTIVE (out)
#define IN_DIM 4096     // ORIG_IN
#define OUT_DIM 4096    // ORIG_OUT
#define SCALING 2.0f    // 32/16

typedef __attribute__((ext_vector_type(8))) short bf16x8_t;  // 8 bf16 = 4 VGPRs
typedef __attribute__((ext_vector_type(4))) float f32x4_t;

__device__ __forceinline__ void load_lds16(const void* gptr, void* lptr) {
    __builtin_amdgcn_global_load_lds(
        (const __attribute__((address_space(1))) uint32_t*)(uintptr_t)gptr,
        (__attribute__((address_space(3))) uint32_t*)(uintptr_t)lptr,
        16, 0, 0);
}

// LDS fragment read with chunk-XOR de-swizzle (matches stage_call's source
// swizzle): p = qd ^ ((row>>1)&3), 64 B row pitch.
__device__ __forceinline__ bf16x8_t frag_ld(const __hip_bfloat16* buf, int row, int qd) {
    const int p = qd ^ ((row >> 1) & 3);
    return *(const bf16x8_t*)(buf + row * 32 + p * 8);
}

// Stage one 8 KB region: 128 rows x 32 bf16 cols, 512 threads x 16B.
// LDS dest linear (wave-uniform base); chunk swizzle applied to the GLOBAL
// source address (both-sides-or-neither rule).
__device__ __forceinline__ void stage_call(const __hip_bfloat16* __restrict__ G,
                                           int grow0,               // global row of region start
                                           __hip_bfloat16* region,  // LDS tile base (row 0)
                                           int lrow0,               // region start row in tile (0/128)
                                           int w, int l, int k0) {
    const int rr   = w * 16 + (l >> 2);        // row within region 0..127
    const int lrow = lrow0 + rr;               // row within 256-row tile (swizzle key)
    const int kc   = (l & 3) ^ ((lrow >> 1) & 3);
    load_lds16(G + (size_t)(grow0 + rr) * K_DIM + k0 + kc * 8,
               (void*)(region + (size_t)(lrow0 + w * 16) * 32));  // wave-uniform
}

// ---------------------------------------------------------------------------
// Kernel P: fused prep.  1-D grid, block-partitioned:
//   [0, 8192)            gather+cast one x-row each
//   [8192, 10240)        fold LoRA into one W-row each
//   [10240, 10256)       inverse index map (binary search)
// ROUND-7 CHANGE (gather only): +1-per-32 padded LDS layout.  Sorted
// half-density indices make lane t read j ~ 16t -> bank (16t)%32 hits only
// {b, b+16} = ~32-way conflict on every scalar read (measured 1.28M conflict
// cycles, 81.5 us @ 1.45 TB/s).  Padded addr j+(j>>5) spreads stride-16
// reads across all 32 banks (<=2-way, free).  Values/order bit-identical.
// ---------------------------------------------------------------------------
__global__ void __launch_bounds__(256)
prep_kernel(const float* __restrict__ x,
            const float* __restrict__ Wb,
            const float* __restrict__ lA,
            const float* __restrict__ lB,
            const int* __restrict__ idx,
            const int* __restrict__ oidx,
            __hip_bfloat16* __restrict__ xs,
            __hip_bfloat16* __restrict__ We,
            int* __restrict__ inv) {
    __shared__ float row[IN_DIM + IN_DIM / 32];   // 4224 f32 = 16.9 KB padded
    const int bid = blockIdx.x;
    const int tid = threadIdx.x;

    if (bid < M_DIM) {
        // ---- gather active input columns + cast bf16 (padded LDS) ----
        const float* xrow = x + (size_t)bid * IN_DIM;
        #pragma unroll
        for (int i = 0; i < 4; ++i) {
            const int c = (i * 256 + tid) * 4;        // c%4==0, same 32-group
            const float4 v = *(const float4*)&xrow[c];
            const int p = c + (c >> 5);               // padded base
            row[p]     = v.x;
            row[p + 1] = v.y;
            row[p + 2] = v.z;
            row[p + 3] = v.w;
        }
        __syncthreads();
        const int c0 = tid * 8;
        int4 i0 = *(const int4*)(idx + c0);
        int4 i1 = *(const int4*)(idx + c0 + 4);
        union { bf16x8_t v; __hip_bfloat16 h[8]; } u;
        u.h[0] = __float2bfloat16(row[i0.x + (i0.x >> 5)]);
        u.h[1] = __float2bfloat16(row[i0.y + (i0.y >> 5)]);
        u.h[2] = __float2bfloat16(row[i0.z + (i0.z >> 5)]);
        u.h[3] = __float2bfloat16(row[i0.w + (i0.w >> 5)]);
        u.h[4] = __float2bfloat16(row[i1.x + (i1.x >> 5)]);
        u.h[5] = __float2bfloat16(row[i1.y + (i1.y >> 5)]);
        u.h[6] = __float2bfloat16(row[i1.z + (i1.z >> 5)]);
        u.h[7] = __float2bfloat16(row[i1.w + (i1.w >> 5)]);
        *(bf16x8_t*)(xs + (size_t)bid * K_DIM + c0) = u.v;
    } else if (bid < M_DIM + N_DIM) {
        // ---- fold LoRA into base weight row, cast bf16 ----
        const int o = bid - M_DIM;
        #pragma unroll
        for (int kk = 0; kk < 8; ++kk) {
            const int k = kk * 256 + tid;
            float acc = Wb[(size_t)o * K_DIM + k];
            #pragma unroll
            for (int r = 0; r < 16; ++r)
                acc += SCALING * lB[o * 16 + r] * lA[r * K_DIM + k];
            We[(size_t)o * K_DIM + k] = __float2bfloat16(acc);
        }
    } else {
        // ---- inverse index map: inv[c] = pos of c in oidx, else -1 ----
        const int c = (bid - M_DIM - N_DIM) * 256 + tid;   // 0..4095
        int lo = 0, hi = N_DIM;
        while (lo < hi) {
            const int mid = (lo + hi) >> 1;
            if (oidx[mid] < c) lo = mid + 1; else hi = mid;
        }
        inv[c] = (lo < N_DIM && oidx[lo] == c) ? lo : -1;
    }
}

// ---------------------------------------------------------------------------
// Kernel G: 256x256 tile GEMM -> compact bf16 C (round-2 body, verbatim).
// 8 waves (2Mx4N), BK=32, quad-buffered LDS (128 KiB), counted-vmcnt
// pipeline: stage tile t+3 into the dead t-1 buffer, vmcnt(8) keeps 2
// K-tiles in flight across the single per-tile barrier.
// ---------------------------------------------------------------------------
__global__ void __launch_bounds__(512, 1)
gemm256_kernel(const __hip_bfloat16* __restrict__ A,   // [M][K] = xs
               const __hip_bfloat16* __restrict__ B,   // [N][K] = W_eff
               const float* __restrict__ bias,         // [N]
               __hip_bfloat16* __restrict__ Cc)        // [M][N] compact
{
    __shared__ __hip_bfloat16 lds[4][2][256 * 32];     // [buf][A=0/B=1] 128 KiB

    const int tid = threadIdx.x;
    const int w   = tid >> 6;        // wave 0..7
    const int l   = tid & 63;
    const int r15 = l & 15;
    const int qd  = l >> 4;
    const int wm  = w >> 2;          // 0..1  (M half: 128 rows)
    const int wn  = w & 3;           // 0..3  (N quarter: 64 cols)
    const int m0  = blockIdx.y * 256;
    const int n0  = blockIdx.x * 256;

    f32x4_t acc[8][4] = {};

    // Prologue: stage K-tiles 0,1,2 (12 vmem instrs/wave).
    #pragma unroll
    for (int t = 0; t < 3; ++t) {
        const int k0 = t * 32;
        stage_call(A, m0,       lds[t][0], 0,   w, l, k0);
        stage_call(A, m0 + 128, lds[t][0], 128, w, l, k0);
        stage_call(B, n0,       lds[t][1], 0,   w, l, k0);
        stage_call(B, n0 + 128, lds[t][1], 128, w, l, k0);
    }
    asm volatile("s_waitcnt vmcnt(8)" ::: "memory");   // tile 0 landed; 1,2 in flight
    __builtin_amdgcn_sched_barrier(0);
    __builtin_amdgcn_s_barrier();

    // Main loop: 64 K-tiles of 32.  Stage index wraps (garbage re-stages into
    // dead, never-again-read buffers for tt+3 >= 64) so vmcnt stays uniform.
    #pragma unroll 4
    for (int tt = 0; tt < 64; ++tt) {
        const int bs  = tt & 3;               // compute buffer
        const int bt  = (tt + 3) & 3;         // stage target = dead t-1 buffer
        const int k0s = ((tt + 3) & 63) * 32;
        const __hip_bfloat16* Ab = lds[bs][0];
        const __hip_bfloat16* Bb = lds[bs][1];

        // Issue ALL fragment loads for this K-tile (16 x ds_read_b128).
        bf16x8_t af[8], bfr[4];
        #pragma unroll
        for (int i = 0; i < 8; ++i)
            af[i] = frag_ld(Ab, wm * 128 + i * 16 + r15, qd);
        #pragma unroll
        for (int j = 0; j < 4; ++j)
            bfr[j] = frag_ld(Bb, wn * 64 + j * 16 + r15, qd);

        // Stage K-tile tt+3 into the dead buffer (4 x global_load_lds).
        stage_call(A, m0,       lds[bt][0], 0,   w, l, k0s);
        stage_call(A, m0 + 128, lds[bt][0], 128, w, l, k0s);
        stage_call(B, n0,       lds[bt][1], 0,   w, l, k0s);
        stage_call(B, n0 + 128, lds[bt][1], 128, w, l, k0s);

        // 32 MFMAs; compiler interleaves ds_read waits (fine-grained lgkmcnt).
        __builtin_amdgcn_s_setprio(1);
        #pragma unroll
        for (int i = 0; i < 8; ++i)
            #pragma unroll
            for (int j = 0; j < 4; ++j)
                acc[i][j] = __builtin_amdgcn_mfma_f32_16x16x32_bf16(
                    af[i], bfr[j], acc[i][j], 0, 0, 0);
        __builtin_amdgcn_s_setprio(0);

        // Counted wait: 8 stage instrs (tiles tt+2, tt+3) stay in flight.
        asm volatile("s_waitcnt vmcnt(8)" ::: "memory");
        __builtin_amdgcn_sched_barrier(0);
        __builtin_amdgcn_s_barrier();
    }
    // Drain outstanding LDS-DMA before LDS goes out of scope.
    asm volatile("s_waitcnt vmcnt(0)" ::: "memory");

    // Epilogue: C/D layout (verified m89/m91): col = lane&15, row = qd*4 + reg
    #pragma unroll
    for (int j = 0; j < 4; ++j) {
        const int gn = n0 + wn * 64 + j * 16 + r15;
        const float bv = bias[gn];
        #pragma unroll
        for (int i = 0; i < 8; ++i) {
            const int gm = m0 + wm * 128 + i * 16 + qd * 4;
            #pragma unroll
            for (int r = 0; r < 4; ++r)
                Cc[(size_t)(gm + r) * N_DIM + gn] =
                    __float2bfloat16(acc[i][j][r] + bv);
        }
    }
}

// ---------------------------------------------------------------------------
// Kernel S: expand compact C into full output (round-0 body, verbatim).
// Fully coalesced float4 writes; replaces any memset.
// ---------------------------------------------------------------------------
__global__ void __launch_bounds__(256)
scatter_out_kernel(const __hip_bfloat16* __restrict__ C,   // [M][N]
                   const int* __restrict__ inv,            // [OUT_DIM]
                   float* __restrict__ out) {              // [M][OUT_DIM]
    const int row = blockIdx.y;
    const int c0 = (blockIdx.x * 256 + threadIdx.x) * 4;
    const __hip_bfloat16* crow = C + (size_t)row * N_DIM;
    const int4 iv = *(const int4*)(inv + c0);
    float4 v;
    v.x = (iv.x >= 0) ? __bfloat162float(crow[iv.x]) : 0.0f;
    v.y = (iv.y >= 0) ? __bfloat162float(crow[iv.y]) : 0.0f;
    v.z = (iv.z >= 0) ? __bfloat162float(crow[iv.z]) : 0.0f;
    v.w = (iv.w >= 0) ? __bfloat162float(crow[iv.w]) : 0.0f;
    *(float4*)(out + (size_t)row * OUT_DIM + c0) = v;
}

// ---------------------------------------------------------------------------
// Fallback GEMM (ws too small): memset + scattered epilogue.
// ---------------------------------------------------------------------------
__global__ void __launch_bounds__(256, 2)
gemm_fallback_kernel(const __hip_bfloat16* __restrict__ A,
                     const __hip_bfloat16* __restrict__ B,
                     const float* __restrict__ bias,
                     const int* __restrict__ oidx,
                     float* __restrict__ out)
{
    __shared__ __hip_bfloat16 As[128 * 64];
    __shared__ __hip_bfloat16 Bs[128 * 64];

    const int tid  = threadIdx.x;
    const int wave = tid >> 6;
    const int lane = tid & 63;
    const int m0 = blockIdx.y * 128;
    const int n0 = blockIdx.x * 128;

    const int wm = (wave >> 1) * 64;
    const int wn = (wave & 1) * 64;

    const int srow  = tid >> 3;
    const int sslot = tid & 7;

    const int r15 = lane & 15;
    const int qd  = lane >> 4;

    f32x4_t acc[4][4] = {};

    for (int k0 = 0; k0 < K_DIM; k0 += 64) {
        #pragma unroll
        for (int it = 0; it < 4; ++it) {
            const int row = it * 32 + srow;
            const int q = sslot ^ (row & 7);
            const __hip_bfloat16* ga = A + (size_t)(m0 + row) * K_DIM + k0 + q * 8;
            const __hip_bfloat16* gb = B + (size_t)(n0 + row) * K_DIM + k0 + q * 8;
            load_lds16(ga, (void*)&As[(it * 32 + wave * 8) * 64]);
            load_lds16(gb, (void*)&Bs[(it * 32 + wave * 8) * 64]);
        }
        __syncthreads();

        #pragma unroll
        for (int s = 0; s < 2; ++s) {
            bf16x8_t af[4], bfr[4];
            #pragma unroll
            for (int i = 0; i < 4; ++i) {
                const int rowa = wm + i * 16 + r15;
                const int pa = (s * 4 + qd) ^ (rowa & 7);
                af[i] = *(const bf16x8_t*)&As[rowa * 64 + pa * 8];
                const int rowb = wn + i * 16 + r15;
                const int pb = (s * 4 + qd) ^ (rowb & 7);
                bfr[i] = *(const bf16x8_t*)&Bs[rowb * 64 + pb * 8];
            }
            #pragma unroll
            for (int i = 0; i < 4; ++i)
                #pragma unroll
                for (int j = 0; j < 4; ++j)
                    acc[i][j] = __builtin_amdgcn_mfma_f32_16x16x32_bf16(
                        af[i], bfr[j], acc[i][j], 0, 0, 0);
        }
        __syncthreads();
    }

    #pragma unroll
    for (int j = 0; j < 4; ++j) {
        const int gn = n0 + wn + j * 16 + r15;
        const float bv = bias[gn];
        const int oc = oidx[gn];
        #pragma unroll
        for (int i = 0; i < 4; ++i) {
            const int gm = m0 + wm + i * 16 + qd * 4;
            #pragma unroll
            for (int r = 0; r < 4; ++r)
                out[(size_t)(gm + r) * OUT_DIM + oc] = acc[i][j][r] + bv;
        }
    }
}

// ---------------------------------------------------------------------------
extern "C" void kernel_launch(void* const* d_in, const int* in_sizes, int n_in,
                              void* d_out, int out_size, void* d_ws, size_t ws_size,
                              hipStream_t stream) {
    const float* x      = (const float*)d_in[0];   // [2,4096,4096]
    const float* W_base = (const float*)d_in[1];   // [2048,2048]
    const float* b_base = (const float*)d_in[2];   // [2048]
    const float* lora_A = (const float*)d_in[3];   // [16,2048]
    const float* lora_B = (const float*)d_in[4];   // [2048,16]
    const int* in_idx   = (const int*)d_in[5];     // [2048]
    const int* out_idx  = (const int*)d_in[6];     // [2048]
    float* out = (float*)d_out;                    // [8192,4096]

    const size_t sz_xs  = (size_t)M_DIM * K_DIM * 2;   // 32 MB
    const size_t sz_We  = (size_t)N_DIM * K_DIM * 2;   //  8 MB
    const size_t sz_C   = (size_t)M_DIM * N_DIM * 2;   // 32 MB
    const size_t sz_inv = (size_t)OUT_DIM * 4;         // 16 KB

    __hip_bfloat16* xs = (__hip_bfloat16*)d_ws;
    __hip_bfloat16* We = (__hip_bfloat16*)((char*)d_ws + sz_xs);
    __hip_bfloat16* Cc = (__hip_bfloat16*)((char*)d_ws + sz_xs + sz_We);
    int* inv           = (int*)((char*)d_ws + sz_xs + sz_We + sz_C);

    if (ws_size >= sz_xs + sz_We + sz_C + sz_inv) {
        // Three dispatches: fused prep -> 256^2 GEMM -> coalesced expand.
        prep_kernel<<<M_DIM + N_DIM + OUT_DIM / 256, 256, 0, stream>>>(
            x, W_base, lora_A, lora_B, in_idx, out_idx, xs, We, inv);
        gemm256_kernel<<<dim3(N_DIM / 256, M_DIM / 256), 512, 0, stream>>>(
            xs, We, b_base, Cc);
        scatter_out_kernel<<<dim3(OUT_DIM / (256 * 4), M_DIM), 256, 0, stream>>>(
            Cc, inv, out);
    } else {
        // Fallback: prep + memset + scattered-epilogue GEMM.
        prep_kernel<<<M_DIM + N_DIM + OUT_DIM / 256, 256, 0, stream>>>(
            x, W_base, lora_A, lora_B, in_idx, out_idx, xs, We, inv);
        hipMemsetAsync(d_out, 0, (size_t)M_DIM * OUT_DIM * sizeof(float), stream);
        gemm_fallback_kernel<<<dim3(N_DIM / 128, M_DIM / 128), 256, 0, stream>>>(
            xs, We, b_base, out_idx, out);
    }
}